// Round 11
// baseline (4053.317 us; speedup 1.0000x reference)
//
#include <hip/hip_runtime.h>
#include <math.h>

#define BB 32     // batch
#define TT 128    // time steps
#define NF 256    // input features
#define HH 512    // hidden
#define G3 1536   // 3*H
#define NWG 64    // GRU workgroups (column partition)

__device__ __forceinline__ float sigmoidf_(float x) { return 1.f / (1.f + __expf(-x)); }
__device__ __forceinline__ float tanh_fast(float x) {
    float e = __expf(2.f * x);
    return 1.f - 2.f / (e + 1.f);
}
__device__ __forceinline__ float sel4_(float a0, float a1, float a2, float a3, int s) {
    float s01 = (s & 1) ? a1 : a0;
    float s23 = (s & 1) ? a3 : a2;
    return (s & 2) ? s23 : s01;
}

// ---------------- K0a: init h double buffer (transpose h0 -> [i][b]) ----------------
__global__ __launch_bounds__(256) void k_hinit(const float* __restrict__ h0,
                                               float* __restrict__ hg2) {
    int idx = blockIdx.x * 256 + threadIdx.x;   // 64 blocks -> 16384
    int i = idx & 511, b = idx >> 9;
    hg2[i * BB + b] = h0[b * HH + i];
}

// ---------------- K0b: pack rk into per-WG swizzled float4 blocks (r10 verbatim) ----------------
__global__ __launch_bounds__(256) void k_pack(const float* __restrict__ rk,
                                              float4* __restrict__ rk4) {
    int gidx = blockIdx.x * 256 + threadIdx.x;   // 1024 blocks -> 262144
    int wg = gidx >> 12;
    int idx = gidx & 4095;
    int k = idx >> 3, s = idx & 7;
    int jjL = s ^ (((k >> 7) & 3) << 1);
    const float* r = rk + (size_t)k * G3 + wg * 8 + jjL;
    rk4[gidx] = make_float4(r[0], r[512], r[1024], 0.f);
}

// ---------------- mx body (shared by upfront kernel and fused role) ----------------
__device__ __forceinline__ void mx_body(const float* __restrict__ data,
                                        const float* __restrict__ gk,
                                        const float* __restrict__ bias_in,
                                        float* __restrict__ mx,
                                        float* __restrict__ xs,   // 8 KB LDS
                                        int t, int b0) {
    int tid = threadIdx.x;
    for (int idx = tid; idx < 8 * NF; idx += 256) {
        int bb = idx >> 8, k = idx & 255;
        xs[k * 8 + bb] = data[((size_t)(b0 + bb) * TT + t) * NF + k];
    }
    __syncthreads();
    float acc[6][8];
#pragma unroll
    for (int jj = 0; jj < 6; jj++)
#pragma unroll
        for (int bb = 0; bb < 8; bb++) acc[jj][bb] = 0.f;

    for (int k = 0; k < NF; k++) {
        float4 xa = *(const float4*)&xs[k * 8];
        float4 xb = *(const float4*)&xs[k * 8 + 4];
        float xv[8] = {xa.x, xa.y, xa.z, xa.w, xb.x, xb.y, xb.z, xb.w};
#pragma unroll
        for (int jj = 0; jj < 6; jj++) {
            float g = gk[(size_t)k * G3 + jj * 256 + tid];
#pragma unroll
            for (int bb = 0; bb < 8; bb++) acc[jj][bb] += g * xv[bb];
        }
    }
#pragma unroll
    for (int jj = 0; jj < 6; jj++) {
        int j = jj * 256 + tid;
        float bi = bias_in[j];
#pragma unroll
        for (int bb = 0; bb < 8; bb++)
            mx[((size_t)t * BB + b0 + bb) * G3 + j] = acc[jj][bb] + bi;
    }
}

// ---------------- K1: upfront mx for t = 0..7 (32 blocks) ----------------
__global__ __launch_bounds__(256) void k_mx8(const float* __restrict__ data,
                                             const float* __restrict__ gk,
                                             const float* __restrict__ bias_in,
                                             float* __restrict__ mx) {
    __shared__ __align__(16) float xs[NF * 8];
    int bx = blockIdx.x;
    mx_body(data, gk, bias_in, mx, xs, bx >> 2, (bx & 3) * 8);
}

// ---------------- K3: sx[b][u][n] (upfront, r10 verbatim) ----------------
__global__ __launch_bounds__(256) void k_sx(const float* __restrict__ data,
                                            const float* __restrict__ w1,
                                            const float* __restrict__ w1b,
                                            float* __restrict__ sx) {
    int bx = blockIdx.x;
    int b = bx >> 4, ug = bx & 15;
    int n = threadIdx.x;
    float acc[8] = {0, 0, 0, 0, 0, 0, 0, 0};
    const float* dp = data + (size_t)b * TT * NF + n;
    for (int t = 0; t < TT; t++) {
        float x = dp[(size_t)t * NF];
#pragma unroll
        for (int uu = 0; uu < 8; uu++) acc[uu] += x * w1[t * TT + ug * 8 + uu];
    }
#pragma unroll
    for (int uu = 0; uu < 8; uu++) {
        int u = ug * 8 + uu;
        sx[((size_t)b * TT + u) * NF + n] = acc[uu] + w1b[u];
    }
}

// ---------------- K_FUSED: one launch per pipeline step ----------------
// blocks 0-63:   GRU step t (r10 k_gstep verbatim + global_load_lds staging)
// blocks 64-67:  mx for t+8
// blocks 68-71:  hp for t-2
// blocks 72-103: attention+output for t-4
extern __shared__ float4 wl4_dyn[];   // 64 KB dynamic, role-dependent use

__global__ __launch_bounds__(256, 1) void k_fused(const float4* __restrict__ rk4,
                                                  const float* __restrict__ gbias,
                                                  float* __restrict__ mx,
                                                  float* __restrict__ hg2,
                                                  float* __restrict__ hs,
                                                  const float* __restrict__ data,
                                                  const float* __restrict__ gk,
                                                  const float* __restrict__ w2,
                                                  const float* __restrict__ w2b,
                                                  const float* __restrict__ sxb,
                                                  float* __restrict__ hpb,
                                                  const float* __restrict__ v_w,
                                                  const float* __restrict__ v_b,
                                                  float* __restrict__ out,
                                                  int t) {
    __shared__ __align__(16) float4 h4[HH * 8];   // 64 KB (gstep role only)
    const int bid = blockIdx.x;
    const int tid = threadIdx.x;

    if (bid < 64) {
        // ================= GRU step role (r10 math verbatim) =================
        if (t >= TT) return;
        const int wg  = bid;
        const int jj  = tid >> 5;
        const int bq  = (tid >> 2) & 7;
        const int ks  = tid & 3;
        const int i0  = wg * 8;
        const int i   = i0 + jj;
        const int batch = bq * 4 + ks;
        const int jjs = jj ^ (ks << 1);
        const int bqs = bq ^ (ks << 1);

        // stage weights: async global->LDS, linear dest (16B/lane)
        {
            const float4* src = rk4 + (size_t)wg * 4096;
#pragma unroll
            for (int it = 0; it < 16; it++) {
                int idx = it * 256 + tid;
                __builtin_amdgcn_global_load_lds(
                    (const __attribute__((address_space(1))) void*)(src + idx),
                    (__attribute__((address_space(3))) void*)&wl4_dyn[idx], 16, 0, 0);
            }
        }
        // stage h: linear LDS dest, PRE-SWIZZLED global source (m173 pattern)
        {
            const float4* hgr = (const float4*)(hg2 + (t & 1) * (HH * BB));
#pragma unroll
            for (int it = 0; it < 16; it++) {
                int idx = it * 256 + tid;
                int sidx = idx ^ ((((idx >> 10) & 3)) << 1);
                __builtin_amdgcn_global_load_lds(
                    (const __attribute__((address_space(1))) void*)(hgr + sidx),
                    (__attribute__((address_space(3))) void*)&h4[idx], 16, 0, 0);
            }
        }
        const float* brec = gbias + G3;
        const float bz = brec[i], br_ = brec[512 + i], bh = brec[1024 + i];
        __syncthreads();   // compiler inserts vmcnt(0) wait for global_load_lds

        const float* mxr = mx + ((size_t)t * BB + batch) * G3;
        float mz = mxr[i], mr = mxr[512 + i], mh = mxr[1024 + i];

        float az0 = 0.f, az1 = 0.f, az2 = 0.f, az3 = 0.f;
        float ar0 = 0.f, ar1 = 0.f, ar2 = 0.f, ar3 = 0.f;
        float ah0 = 0.f, ah1 = 0.f, ah2 = 0.f, ah3 = 0.f;
        const float4* wp  = wl4_dyn + ks * 1024 + jjs;
        const float4* hp2 = &h4[ks * 1024 + bqs];
#pragma unroll 4
        for (int kk = 0; kk < 128; kk++) {
            float4 w = wp[kk * 8];
            float4 h = hp2[kk * 8];
            az0 += w.x * h.x; az1 += w.x * h.y; az2 += w.x * h.z; az3 += w.x * h.w;
            ar0 += w.y * h.x; ar1 += w.y * h.y; ar2 += w.y * h.z; ar3 += w.y * h.w;
            ah0 += w.z * h.x; ah1 += w.z * h.y; ah2 += w.z * h.z; ah3 += w.z * h.w;
        }

        az0 += __shfl_xor(az0, 1); az1 += __shfl_xor(az1, 1);
        az2 += __shfl_xor(az2, 1); az3 += __shfl_xor(az3, 1);
        ar0 += __shfl_xor(ar0, 1); ar1 += __shfl_xor(ar1, 1);
        ar2 += __shfl_xor(ar2, 1); ar3 += __shfl_xor(ar3, 1);
        ah0 += __shfl_xor(ah0, 1); ah1 += __shfl_xor(ah1, 1);
        ah2 += __shfl_xor(ah2, 1); ah3 += __shfl_xor(ah3, 1);
        az0 += __shfl_xor(az0, 2); az1 += __shfl_xor(az1, 2);
        az2 += __shfl_xor(az2, 2); az3 += __shfl_xor(az3, 2);
        ar0 += __shfl_xor(ar0, 2); ar1 += __shfl_xor(ar1, 2);
        ar2 += __shfl_xor(ar2, 2); ar3 += __shfl_xor(ar3, 2);
        ah0 += __shfl_xor(ah0, 2); ah1 += __shfl_xor(ah1, 2);
        ah2 += __shfl_xor(ah2, 2); ah3 += __shfl_xor(ah3, 2);

        float azt = sel4_(az0, az1, az2, az3, ks);
        float art = sel4_(ar0, ar1, ar2, ar3, ks);
        float aht = sel4_(ah0, ah1, ah2, ah3, ks);

        float z = sigmoidf_(mz + azt + bz);
        float r = sigmoidf_(mr + art + br_);
        float c = tanhf(mh + r * (aht + bh));
        float hold = ((const float*)&h4[i * 8 + (bq ^ ((((i >> 7) & 3)) << 1))])[ks];
        float hn = z * hold + (1.f - z) * c;

        hg2[((t + 1) & 1) * (HH * BB) + i * BB + batch] = hn;
        hs[((size_t)t * BB + batch) * HH + i] = hn;

    } else if (bid < 68) {
        // ================= mx role: compute mx[t+8] =================
        int tm = t + 8;
        if (tm >= TT) return;
        float* xs = (float*)wl4_dyn;   // 8 KB of the dynamic region
        mx_body(data, gk, gbias, mx, xs, tm, (bid - 64) * 8);

    } else if (bid < 72) {
        // ================= hp role: hp rows for th = t-2 =================
        int th = t - 2;
        if (th < 0 || th >= TT) return;
        float* hsl = (float*)wl4_dyn;   // 16 KB
        int r0 = th * 32 + (bid - 68) * 8;
        for (int idx = tid; idx < 8 * HH; idx += 256)
            hsl[idx] = hs[(size_t)r0 * HH + idx];
        __syncthreads();
        int u = tid & 127, rh = tid >> 7;
        float acc[4] = {0, 0, 0, 0};
        for (int k = 0; k < HH; k++) {
            float w = w2[k * TT + u];
#pragma unroll
            for (int rr = 0; rr < 4; rr++) acc[rr] += hsl[(rh * 4 + rr) * HH + k] * w;
        }
        float wb = w2b[u];
#pragma unroll
        for (int rr = 0; rr < 4; rr++)
            hpb[(size_t)(r0 + rh * 4 + rr) * TT + u] = acc[rr] + wb;

    } else {
        // ================= attn role: output rows for ta = t-4 =================
        int ta = t - 4;
        if (ta < 0 || ta >= TT) return;
        float* hv = (float*)wl4_dyn;          // 128
        float* vv = hv + TT;                  // 128
        float* red = vv + TT;                 // 8
        int r = ta * 32 + (bid - 72);
        int b = r & 31;
        int n = tid;
        if (n < TT) {
            hv[n] = hpb[(size_t)r * TT + n];
            vv[n] = v_w[n];
        }
        __syncthreads();
        float s = v_b[0];
        const float* sxp = sxb + (size_t)b * TT * NF + n;
        for (int u = 0; u < TT; u++) {
            float e = tanh_fast(sxp[(size_t)u * NF] + hv[u]);
            s += vv[u] * e;
        }
        float m = s;
#pragma unroll
        for (int off = 32; off >= 1; off >>= 1) m = fmaxf(m, __shfl_xor(m, off));
        int lane = n & 63, wid = n >> 6;
        if (lane == 0) red[wid] = m;
        __syncthreads();
        float bm = fmaxf(fmaxf(red[0], red[1]), fmaxf(red[2], red[3]));
        float p = __expf(s - bm);
        float ps = p;
#pragma unroll
        for (int off = 32; off >= 1; off >>= 1) ps += __shfl_xor(ps, off);
        if (lane == 0) red[4 + wid] = ps;
        __syncthreads();
        float denom = red[4] + red[5] + red[6] + red[7];
        float alpha = p / denom;
        size_t idx = (size_t)r * NF + n;
        out[idx] = data[idx] * alpha;
    }
}

extern "C" void kernel_launch(void* const* d_in, const int* in_sizes, int n_in,
                              void* d_out, int out_size, void* d_ws, size_t ws_size,
                              hipStream_t stream) {
    const float* data = (const float*)d_in[0];
    const float* h0   = (const float*)d_in[1];
    const float* gk   = (const float*)d_in[2];
    const float* rk   = (const float*)d_in[3];
    const float* gb   = (const float*)d_in[4];
    const float* w1   = (const float*)d_in[5];
    const float* w1b  = (const float*)d_in[6];
    const float* w2   = (const float*)d_in[7];
    const float* w2b  = (const float*)d_in[8];
    const float* vw   = (const float*)d_in[9];
    const float* vb   = (const float*)d_in[10];
    float* out = (float*)d_out;

    float* ws  = (float*)d_ws;
    float* mx  = ws;                    // 128*32*1536 = 6291456
    float* hs  = mx + 6291456;          // 128*32*512  = 2097152
    float* sxb = hs + 2097152;          // 32*128*256  = 1048576
    float* hpb = sxb + 1048576;         // 128*32*128  = 524288
    float* hg2 = hpb + 524288;          // 2*512*32    = 32768
    float4* rk4 = (float4*)(hg2 + 32768);   // 262144 float4 = 4 MB

    k_hinit<<<64, 256, 0, stream>>>(h0, hg2);
    k_pack<<<1024, 256, 0, stream>>>(rk, rk4);
    k_mx8<<<32, 256, 0, stream>>>(data, gk, gb, mx);     // mx for t = 0..7
    k_sx<<<512, 256, 0, stream>>>(data, w1, w1b, sxb);   // sx upfront (no GRU dep)

    for (int t = 0; t < TT + 4; t++)
        k_fused<<<104, 256, 65536, stream>>>(rk4, gb, mx, hg2, hs,
                                             data, gk, w2, w2b, sxb, hpb,
                                             vw, vb, out, t);
}

// Round 12
// 2106.328 us; speedup vs baseline: 1.9244x; 1.9244x over previous
//
#include <hip/hip_runtime.h>
#include <math.h>

#define BB 32     // batch
#define TT 128    // time steps
#define NF 256    // input features
#define HH 512    // hidden
#define G3 1536   // 3*H
#define NWG 64    // GRU workgroups (column partition)

__device__ __forceinline__ float sigmoidf_(float x) { return 1.f / (1.f + __expf(-x)); }
__device__ __forceinline__ float tanh_fast(float x) {
    float e = __expf(2.f * x);
    return 1.f - 2.f / (e + 1.f);
}
__device__ __forceinline__ float sel4_(float a0, float a1, float a2, float a3, int s) {
    float s01 = (s & 1) ? a1 : a0;
    float s23 = (s & 1) ? a3 : a2;
    return (s & 2) ? s23 : s01;
}

// ---------------- K0a: init h double buffer (transpose h0 -> [i][b]) ----------------
__global__ __launch_bounds__(256) void k_hinit(const float* __restrict__ h0,
                                               float* __restrict__ hg2) {
    int idx = blockIdx.x * 256 + threadIdx.x;   // 64 blocks -> 16384
    int i = idx & 511, b = idx >> 9;
    hg2[i * BB + b] = h0[b * HH + i];
}

// ---------------- K0b: pack rk into per-WG swizzled float4 blocks (r10 verbatim) ----------------
__global__ __launch_bounds__(256) void k_pack(const float* __restrict__ rk,
                                              float4* __restrict__ rk4) {
    int gidx = blockIdx.x * 256 + threadIdx.x;   // 1024 blocks -> 262144
    int wg = gidx >> 12;
    int idx = gidx & 4095;
    int k = idx >> 3, s = idx & 7;
    int jjL = s ^ (((k >> 7) & 3) << 1);
    const float* r = rk + (size_t)k * G3 + wg * 8 + jjL;
    rk4[gidx] = make_float4(r[0], r[512], r[1024], 0.f);
}

// ---------------- K1: mx[t][b][j] — FULL upfront GEMM (r10 verbatim, 512 blocks) ----------------
__global__ __launch_bounds__(256) void k_mx(const float* __restrict__ data,
                                            const float* __restrict__ gk,
                                            const float* __restrict__ bias_in,
                                            float* __restrict__ mx) {
    __shared__ __align__(16) float xs[NF * 8];   // [k][bb]
    int bx = blockIdx.x;
    int t = bx >> 2, b0 = (bx & 3) * 8;
    int tid = threadIdx.x;
    for (int idx = tid; idx < 8 * NF; idx += 256) {
        int bb = idx >> 8, k = idx & 255;
        xs[k * 8 + bb] = data[((size_t)(b0 + bb) * TT + t) * NF + k];
    }
    __syncthreads();
    float acc[6][8];
#pragma unroll
    for (int jj = 0; jj < 6; jj++)
#pragma unroll
        for (int bb = 0; bb < 8; bb++) acc[jj][bb] = 0.f;

    for (int k = 0; k < NF; k++) {
        float4 xa = *(const float4*)&xs[k * 8];
        float4 xb = *(const float4*)&xs[k * 8 + 4];
        float xv[8] = {xa.x, xa.y, xa.z, xa.w, xb.x, xb.y, xb.z, xb.w};
#pragma unroll
        for (int jj = 0; jj < 6; jj++) {
            float g = gk[(size_t)k * G3 + jj * 256 + tid];
#pragma unroll
            for (int bb = 0; bb < 8; bb++) acc[jj][bb] += g * xv[bb];
        }
    }
#pragma unroll
    for (int jj = 0; jj < 6; jj++) {
        int j = jj * 256 + tid;
        float bi = bias_in[j];
#pragma unroll
        for (int bb = 0; bb < 8; bb++)
            mx[((size_t)t * BB + b0 + bb) * G3 + j] = acc[jj][bb] + bi;
    }
}

// ---------------- K3: sx[b][u][n] (upfront, r10 verbatim) ----------------
__global__ __launch_bounds__(256) void k_sx(const float* __restrict__ data,
                                            const float* __restrict__ w1,
                                            const float* __restrict__ w1b,
                                            float* __restrict__ sx) {
    int bx = blockIdx.x;
    int b = bx >> 4, ug = bx & 15;
    int n = threadIdx.x;
    float acc[8] = {0, 0, 0, 0, 0, 0, 0, 0};
    const float* dp = data + (size_t)b * TT * NF + n;
    for (int t = 0; t < TT; t++) {
        float x = dp[(size_t)t * NF];
#pragma unroll
        for (int uu = 0; uu < 8; uu++) acc[uu] += x * w1[t * TT + ug * 8 + uu];
    }
#pragma unroll
    for (int uu = 0; uu < 8; uu++) {
        int u = ug * 8 + uu;
        sx[((size_t)b * TT + u) * NF + n] = acc[uu] + w1b[u];
    }
}

// ---------------- K_FUSED: one launch per pipeline step ----------------
// blocks 0-63:  GRU step t (r10 math verbatim, global_load_lds staging)
// blocks 64-67: hp rows for t-2      (per-block ~3 us  < gstep)
// blocks 68-99: attention+out, t-4   (per-block ~2 us  < gstep)
extern __shared__ float4 wl4_dyn[];   // 64 KB dynamic, role-dependent use

__global__ __launch_bounds__(256, 1) void k_fused(const float4* __restrict__ rk4,
                                                  const float* __restrict__ gbias,
                                                  const float* __restrict__ mx,
                                                  float* __restrict__ hg2,
                                                  float* __restrict__ hs,
                                                  const float* __restrict__ data,
                                                  const float* __restrict__ w2,
                                                  const float* __restrict__ w2b,
                                                  const float* __restrict__ sxb,
                                                  float* __restrict__ hpb,
                                                  const float* __restrict__ v_w,
                                                  const float* __restrict__ v_b,
                                                  float* __restrict__ out,
                                                  int t) {
    __shared__ __align__(16) float4 h4[HH * 8];   // 64 KB (gstep role only)
    const int bid = blockIdx.x;
    const int tid = threadIdx.x;

    if (bid < 64) {
        // ================= GRU step role (r10 math verbatim) =================
        if (t >= TT) return;
        const int wg  = bid;
        const int jj  = tid >> 5;
        const int bq  = (tid >> 2) & 7;
        const int ks  = tid & 3;
        const int i0  = wg * 8;
        const int i   = i0 + jj;
        const int batch = bq * 4 + ks;
        const int jjs = jj ^ (ks << 1);
        const int bqs = bq ^ (ks << 1);

        // stage weights: async global->LDS, linear dest (16B/lane)
        {
            const float4* src = rk4 + (size_t)wg * 4096;
#pragma unroll
            for (int it = 0; it < 16; it++) {
                int idx = it * 256 + tid;
                __builtin_amdgcn_global_load_lds(
                    (const __attribute__((address_space(1))) void*)(src + idx),
                    (__attribute__((address_space(3))) void*)&wl4_dyn[idx], 16, 0, 0);
            }
        }
        // stage h: linear LDS dest, PRE-SWIZZLED global source (m173 pattern)
        {
            const float4* hgr = (const float4*)(hg2 + (t & 1) * (HH * BB));
#pragma unroll
            for (int it = 0; it < 16; it++) {
                int idx = it * 256 + tid;
                int sidx = idx ^ ((((idx >> 10) & 3)) << 1);
                __builtin_amdgcn_global_load_lds(
                    (const __attribute__((address_space(1))) void*)(hgr + sidx),
                    (__attribute__((address_space(3))) void*)&h4[idx], 16, 0, 0);
            }
        }
        const float* brec = gbias + G3;
        const float bz = brec[i], br_ = brec[512 + i], bh = brec[1024 + i];
        __syncthreads();   // compiler inserts vmcnt(0) wait for global_load_lds

        const float* mxr = mx + ((size_t)t * BB + batch) * G3;
        float mz = mxr[i], mr = mxr[512 + i], mh = mxr[1024 + i];

        float az0 = 0.f, az1 = 0.f, az2 = 0.f, az3 = 0.f;
        float ar0 = 0.f, ar1 = 0.f, ar2 = 0.f, ar3 = 0.f;
        float ah0 = 0.f, ah1 = 0.f, ah2 = 0.f, ah3 = 0.f;
        const float4* wp  = wl4_dyn + ks * 1024 + jjs;
        const float4* hp2 = &h4[ks * 1024 + bqs];
#pragma unroll 4
        for (int kk = 0; kk < 128; kk++) {
            float4 w = wp[kk * 8];
            float4 h = hp2[kk * 8];
            az0 += w.x * h.x; az1 += w.x * h.y; az2 += w.x * h.z; az3 += w.x * h.w;
            ar0 += w.y * h.x; ar1 += w.y * h.y; ar2 += w.y * h.z; ar3 += w.y * h.w;
            ah0 += w.z * h.x; ah1 += w.z * h.y; ah2 += w.z * h.z; ah3 += w.z * h.w;
        }

        az0 += __shfl_xor(az0, 1); az1 += __shfl_xor(az1, 1);
        az2 += __shfl_xor(az2, 1); az3 += __shfl_xor(az3, 1);
        ar0 += __shfl_xor(ar0, 1); ar1 += __shfl_xor(ar1, 1);
        ar2 += __shfl_xor(ar2, 1); ar3 += __shfl_xor(ar3, 1);
        ah0 += __shfl_xor(ah0, 1); ah1 += __shfl_xor(ah1, 1);
        ah2 += __shfl_xor(ah2, 1); ah3 += __shfl_xor(ah3, 1);
        az0 += __shfl_xor(az0, 2); az1 += __shfl_xor(az1, 2);
        az2 += __shfl_xor(az2, 2); az3 += __shfl_xor(az3, 2);
        ar0 += __shfl_xor(ar0, 2); ar1 += __shfl_xor(ar1, 2);
        ar2 += __shfl_xor(ar2, 2); ar3 += __shfl_xor(ar3, 2);
        ah0 += __shfl_xor(ah0, 2); ah1 += __shfl_xor(ah1, 2);
        ah2 += __shfl_xor(ah2, 2); ah3 += __shfl_xor(ah3, 2);

        float azt = sel4_(az0, az1, az2, az3, ks);
        float art = sel4_(ar0, ar1, ar2, ar3, ks);
        float aht = sel4_(ah0, ah1, ah2, ah3, ks);

        float z = sigmoidf_(mz + azt + bz);
        float r = sigmoidf_(mr + art + br_);
        float c = tanhf(mh + r * (aht + bh));
        float hold = ((const float*)&h4[i * 8 + (bq ^ ((((i >> 7) & 3)) << 1))])[ks];
        float hn = z * hold + (1.f - z) * c;

        hg2[((t + 1) & 1) * (HH * BB) + i * BB + batch] = hn;
        hs[((size_t)t * BB + batch) * HH + i] = hn;

    } else if (bid < 68) {
        // ================= hp role: hp rows for th = t-2 =================
        int th = t - 2;
        if (th < 0 || th >= TT) return;
        float* hsl = (float*)wl4_dyn;   // 16 KB
        int r0 = th * 32 + (bid - 64) * 8;
        for (int idx = tid; idx < 8 * HH; idx += 256)
            hsl[idx] = hs[(size_t)r0 * HH + idx];
        __syncthreads();
        int u = tid & 127, rh = tid >> 7;
        float acc[4] = {0, 0, 0, 0};
        for (int k = 0; k < HH; k++) {
            float w = w2[k * TT + u];
#pragma unroll
            for (int rr = 0; rr < 4; rr++) acc[rr] += hsl[(rh * 4 + rr) * HH + k] * w;
        }
        float wb = w2b[u];
#pragma unroll
        for (int rr = 0; rr < 4; rr++)
            hpb[(size_t)(r0 + rh * 4 + rr) * TT + u] = acc[rr] + wb;

    } else {
        // ================= attn role: output rows for ta = t-4 =================
        int ta = t - 4;
        if (ta < 0 || ta >= TT) return;
        float* hv = (float*)wl4_dyn;          // 128
        float* vv = hv + TT;                  // 128
        float* red = vv + TT;                 // 8
        int r = ta * 32 + (bid - 68);
        int b = r & 31;
        int n = tid;
        if (n < TT) {
            hv[n] = hpb[(size_t)r * TT + n];
            vv[n] = v_w[n];
        }
        __syncthreads();
        float s = v_b[0];
        const float* sxp = sxb + (size_t)b * TT * NF + n;
        for (int u = 0; u < TT; u++) {
            float e = tanh_fast(sxp[(size_t)u * NF] + hv[u]);
            s += vv[u] * e;
        }
        float m = s;
#pragma unroll
        for (int off = 32; off >= 1; off >>= 1) m = fmaxf(m, __shfl_xor(m, off));
        int lane = n & 63, wid = n >> 6;
        if (lane == 0) red[wid] = m;
        __syncthreads();
        float bm = fmaxf(fmaxf(red[0], red[1]), fmaxf(red[2], red[3]));
        float p = __expf(s - bm);
        float ps = p;
#pragma unroll
        for (int off = 32; off >= 1; off >>= 1) ps += __shfl_xor(ps, off);
        if (lane == 0) red[4 + wid] = ps;
        __syncthreads();
        float denom = red[4] + red[5] + red[6] + red[7];
        float alpha = p / denom;
        size_t idx = (size_t)r * NF + n;
        out[idx] = data[idx] * alpha;
    }
}

extern "C" void kernel_launch(void* const* d_in, const int* in_sizes, int n_in,
                              void* d_out, int out_size, void* d_ws, size_t ws_size,
                              hipStream_t stream) {
    const float* data = (const float*)d_in[0];
    const float* h0   = (const float*)d_in[1];
    const float* gk   = (const float*)d_in[2];
    const float* rk   = (const float*)d_in[3];
    const float* gb   = (const float*)d_in[4];
    const float* w1   = (const float*)d_in[5];
    const float* w1b  = (const float*)d_in[6];
    const float* w2   = (const float*)d_in[7];
    const float* w2b  = (const float*)d_in[8];
    const float* vw   = (const float*)d_in[9];
    const float* vb   = (const float*)d_in[10];
    float* out = (float*)d_out;

    float* ws  = (float*)d_ws;
    float* mx  = ws;                    // 128*32*1536 = 6291456
    float* hs  = mx + 6291456;          // 128*32*512  = 2097152
    float* sxb = hs + 2097152;          // 32*128*256  = 1048576
    float* hpb = sxb + 1048576;         // 128*32*128  = 524288
    float* hg2 = hpb + 524288;          // 2*512*32    = 32768
    float4* rk4 = (float4*)(hg2 + 32768);   // 262144 float4 = 4 MB

    k_hinit<<<64, 256, 0, stream>>>(h0, hg2);
    k_pack<<<1024, 256, 0, stream>>>(rk, rk4);
    k_mx<<<512, 256, 0, stream>>>(data, gk, gb, mx);     // ALL mx upfront (r10-proven)
    k_sx<<<512, 256, 0, stream>>>(data, w1, w1b, sxb);   // sx upfront (no GRU dep)

    for (int t = 0; t < TT + 4; t++)
        k_fused<<<100, 256, 65536, stream>>>(rk4, gb, mx, hg2, hs,
                                             data, w2, w2b, sxb, hpb,
                                             vw, vb, out, t);
}

// Round 13
// 1277.569 us; speedup vs baseline: 3.1727x; 1.6487x over previous
//
#include <hip/hip_runtime.h>
#include <math.h>

#define BB 32     // batch
#define TT 128    // time steps
#define NF 256    // input features
#define HH 512    // hidden
#define G3 1536   // 3*H
#define NWG 64    // GRU workgroups (column partition)

__device__ __forceinline__ float sigmoidf_(float x) { return 1.f / (1.f + __expf(-x)); }
__device__ __forceinline__ float tanh_fast(float x) {
    float e = __expf(2.f * x);
    return 1.f - 2.f / (e + 1.f);
}
__device__ __forceinline__ float sel4_(float a0, float a1, float a2, float a3, int s) {
    float s01 = (s & 1) ? a1 : a0;
    float s23 = (s & 1) ? a3 : a2;
    return (s & 2) ? s23 : s01;
}

// ---------------- K0a: init h double buffer (transpose h0 -> [i][b]) ----------------
__global__ __launch_bounds__(256) void k_hinit(const float* __restrict__ h0,
                                               float* __restrict__ hg2) {
    int idx = blockIdx.x * 256 + threadIdx.x;   // 64 blocks -> 16384
    int i = idx & 511, b = idx >> 9;
    hg2[i * BB + b] = h0[b * HH + i];
}

// ---------------- K0b: pack rk into per-WG swizzled float4 blocks (r10 verbatim) ----------------
__global__ __launch_bounds__(256) void k_pack(const float* __restrict__ rk,
                                              float4* __restrict__ rk4) {
    int gidx = blockIdx.x * 256 + threadIdx.x;   // 1024 blocks -> 262144
    int wg = gidx >> 12;
    int idx = gidx & 4095;
    int k = idx >> 3, s = idx & 7;
    int jjL = s ^ (((k >> 7) & 3) << 1);
    const float* r = rk + (size_t)k * G3 + wg * 8 + jjL;
    rk4[gidx] = make_float4(r[0], r[512], r[1024], 0.f);
}

// ---------------- K1: mxT[t][j][b] = data[b][t][:] @ gru_kernel + b_in (TRANSPOSED out) ----------------
__global__ __launch_bounds__(256) void k_mx(const float* __restrict__ data,
                                            const float* __restrict__ gk,
                                            const float* __restrict__ bias_in,
                                            float* __restrict__ mxT) {
    __shared__ __align__(16) float xs[NF * 8];   // [k][bb]
    int bx = blockIdx.x;
    int t = bx >> 2, b0 = (bx & 3) * 8;
    int tid = threadIdx.x;
    for (int idx = tid; idx < 8 * NF; idx += 256) {
        int bb = idx >> 8, k = idx & 255;
        xs[k * 8 + bb] = data[((size_t)(b0 + bb) * TT + t) * NF + k];
    }
    __syncthreads();
    float acc[6][8];
#pragma unroll
    for (int jj = 0; jj < 6; jj++)
#pragma unroll
        for (int bb = 0; bb < 8; bb++) acc[jj][bb] = 0.f;

    for (int k = 0; k < NF; k++) {
        float4 xa = *(const float4*)&xs[k * 8];
        float4 xb = *(const float4*)&xs[k * 8 + 4];
        float xv[8] = {xa.x, xa.y, xa.z, xa.w, xb.x, xb.y, xb.z, xb.w};
#pragma unroll
        for (int jj = 0; jj < 6; jj++) {
            float g = gk[(size_t)k * G3 + jj * 256 + tid];
#pragma unroll
            for (int bb = 0; bb < 8; bb++) acc[jj][bb] += g * xv[bb];
        }
    }
#pragma unroll
    for (int jj = 0; jj < 6; jj++) {
        int j = jj * 256 + tid;
        float bi = bias_in[j];
#pragma unroll
        for (int bb = 0; bb < 8; bb++)
            mxT[((size_t)t * G3 + j) * BB + b0 + bb] = acc[jj][bb] + bi;   // [t][j][b]
    }
}

// ---------------- K2: ONE GRU STEP per launch — r10 compute verbatim; coalesced mxT + hs ----------------
extern __shared__ float4 wl4_dyn[];   // 4096 float4 = 64 KB, r10 swizzled weight layout

__global__ __launch_bounds__(256, 1) void k_gstep(const float4* __restrict__ rk4,
                                                  const float* __restrict__ gbias,
                                                  const float* __restrict__ mxT,
                                                  float* __restrict__ hg2,
                                                  float* __restrict__ hs,
                                                  int t) {
    __shared__ __align__(16) float4 h4[HH * 8];   // 64 KB: h[k][batch-quad], swizzled
    const int tid = threadIdx.x;
    const int wg  = blockIdx.x;
    const int jj  = tid >> 5;          // 0..7 column within slice
    const int bq  = (tid >> 2) & 7;    // 0..7 batch quad
    const int ks  = tid & 3;           // 0..3 k-split (128 k each)
    const int i0  = wg * 8;
    const int i   = i0 + jj;
    const int batch = bq * 4 + ks;
    const int jjs = jj ^ (ks << 1);    // swizzled weight slot for this thread's k-range
    const int bqs = bq ^ (ks << 1);    // swizzled h slot for this thread's k-range

    // ---- stage weight slice: contiguous 64 KB copy (prepacked, swizzle baked in) ----
    {
        const float4* src = rk4 + (size_t)wg * 4096;
#pragma unroll
        for (int it = 0; it < 16; it++) {
            int idx = it * 256 + tid;
            wl4_dyn[idx] = src[idx];
        }
    }
    // ---- stage h[t&1] -> LDS, swizzled (r10 verbatim) ----
    {
        const float4* hgr = (const float4*)(hg2 + (t & 1) * (HH * BB));
#pragma unroll
        for (int it = 0; it < 16; it++) {
            int idx = it * 256 + tid;
            h4[idx] = hgr[idx ^ ((((idx >> 10) & 3)) << 1)];
        }
    }
    const float* brec = gbias + G3;
    const float bz = brec[i], br_ = brec[512 + i], bh = brec[1024 + i];
    __syncthreads();

    // mx loads — coalesced from mxT[t][j][b] (wave reads 256B contiguous per gate)
    const float* mxc = mxT + (size_t)t * G3 * BB;
    float mz = mxc[(size_t)i * BB + batch];
    float mr = mxc[(size_t)(512 + i) * BB + batch];
    float mh = mxc[(size_t)(1024 + i) * BB + batch];

    // ---- inner: 128 k per thread, 2 b128 reads + 12 FMA per k (r10 verbatim) ----
    float az0 = 0.f, az1 = 0.f, az2 = 0.f, az3 = 0.f;
    float ar0 = 0.f, ar1 = 0.f, ar2 = 0.f, ar3 = 0.f;
    float ah0 = 0.f, ah1 = 0.f, ah2 = 0.f, ah3 = 0.f;
    const float4* wp  = wl4_dyn + ks * 1024 + jjs;
    const float4* hp2 = &h4[ks * 1024 + bqs];
#pragma unroll 4
    for (int kk = 0; kk < 128; kk++) {
        float4 w = wp[kk * 8];     // {wz,wr,wc,_} col jj, k=ks*128+kk (8-way broadcast)
        float4 h = hp2[kk * 8];    // h[k][bq*4 .. bq*4+3]
        az0 += w.x * h.x; az1 += w.x * h.y; az2 += w.x * h.z; az3 += w.x * h.w;
        ar0 += w.y * h.x; ar1 += w.y * h.y; ar2 += w.y * h.z; ar3 += w.y * h.w;
        ah0 += w.z * h.x; ah1 += w.z * h.y; ah2 += w.z * h.z; ah3 += w.z * h.w;
    }

    // ---- in-wave butterfly over ks lanes (r10 verbatim) ----
    az0 += __shfl_xor(az0, 1); az1 += __shfl_xor(az1, 1);
    az2 += __shfl_xor(az2, 1); az3 += __shfl_xor(az3, 1);
    ar0 += __shfl_xor(ar0, 1); ar1 += __shfl_xor(ar1, 1);
    ar2 += __shfl_xor(ar2, 1); ar3 += __shfl_xor(ar3, 1);
    ah0 += __shfl_xor(ah0, 1); ah1 += __shfl_xor(ah1, 1);
    ah2 += __shfl_xor(ah2, 1); ah3 += __shfl_xor(ah3, 1);
    az0 += __shfl_xor(az0, 2); az1 += __shfl_xor(az1, 2);
    az2 += __shfl_xor(az2, 2); az3 += __shfl_xor(az3, 2);
    ar0 += __shfl_xor(ar0, 2); ar1 += __shfl_xor(ar1, 2);
    ar2 += __shfl_xor(ar2, 2); ar3 += __shfl_xor(ar3, 2);
    ah0 += __shfl_xor(ah0, 2); ah1 += __shfl_xor(ah1, 2);
    ah2 += __shfl_xor(ah2, 2); ah3 += __shfl_xor(ah3, 2);

    float azt = sel4_(az0, az1, az2, az3, ks);
    float art = sel4_(ar0, ar1, ar2, ar3, ks);
    float aht = sel4_(ah0, ah1, ah2, ah3, ks);

    float z = sigmoidf_(mz + azt + bz);
    float r = sigmoidf_(mr + art + br_);
    float c = tanhf(mh + r * (aht + bh));
    float hold = ((const float*)&h4[i * 8 + (bq ^ ((((i >> 7) & 3)) << 1))])[ks];
    float hn = z * hold + (1.f - z) * c;

    hg2[((t + 1) & 1) * (HH * BB) + i * BB + batch] = hn;   // coalesced across ks,bq

    // ---- hs store via LDS transpose (weights done -> reuse wl4_dyn region) ----
    __syncthreads();                        // all inner-loop weight reads complete
    float* hstage = (float*)wl4_dyn;
    hstage[jj * 36 + batch] = hn;           // conflict-free (pad 36)
    __syncthreads();
    {
        int b2 = tid >> 3, ii = tid & 7;    // 32B-segment stores (8 lanes/segment)
        hs[((size_t)t * BB + b2) * HH + i0 + ii] = hstage[ii * 36 + b2];
    }
}

// ---------------- K3: sx[b][u][n] (upfront, r10 verbatim) ----------------
__global__ __launch_bounds__(256) void k_sx(const float* __restrict__ data,
                                            const float* __restrict__ w1,
                                            const float* __restrict__ w1b,
                                            float* __restrict__ sx) {
    int bx = blockIdx.x;
    int b = bx >> 4, ug = bx & 15;
    int n = threadIdx.x;
    float acc[8] = {0, 0, 0, 0, 0, 0, 0, 0};
    const float* dp = data + (size_t)b * TT * NF + n;
    for (int t = 0; t < TT; t++) {
        float x = dp[(size_t)t * NF];
#pragma unroll
        for (int uu = 0; uu < 8; uu++) acc[uu] += x * w1[t * TT + ug * 8 + uu];
    }
#pragma unroll
    for (int uu = 0; uu < 8; uu++) {
        int u = ug * 8 + uu;
        sx[((size_t)b * TT + u) * NF + n] = acc[uu] + w1b[u];
    }
}

// ---------------- K4: hp[r][u] = hs[r][:] @ w2 + w2b  (r = t*32+b, r10 verbatim) ----------------
__global__ __launch_bounds__(256) void k_hp(const float* __restrict__ hs,
                                            const float* __restrict__ w2,
                                            const float* __restrict__ w2b,
                                            float* __restrict__ hp) {
    __shared__ float hsl[8 * HH];   // 16KB
    int r0 = blockIdx.x * 8;
    int tid = threadIdx.x;
    for (int idx = tid; idx < 8 * HH; idx += 256)
        hsl[idx] = hs[(size_t)r0 * HH + idx];
    __syncthreads();
    int u = tid & 127, rh = tid >> 7;
    float acc[4] = {0, 0, 0, 0};
    for (int k = 0; k < HH; k++) {
        float w = w2[k * TT + u];
#pragma unroll
        for (int rr = 0; rr < 4; rr++) acc[rr] += hsl[(rh * 4 + rr) * HH + k] * w;
    }
    float wb = w2b[u];
#pragma unroll
    for (int rr = 0; rr < 4; rr++)
        hp[(size_t)(r0 + rh * 4 + rr) * TT + u] = acc[rr] + wb;
}

// ---------------- K5: fused score + softmax + output (r10 verbatim) ----------------
__global__ __launch_bounds__(256) void k_attn(const float* __restrict__ data,
                                              const float* __restrict__ sx,
                                              const float* __restrict__ hp,
                                              const float* __restrict__ v_w,
                                              const float* __restrict__ v_b,
                                              float* __restrict__ out) {
    __shared__ float hv[TT];
    __shared__ float vv[TT];
    __shared__ float red[8];
    int r = blockIdx.x;
    int b = r & 31;
    int n = threadIdx.x;
    if (n < TT) {
        hv[n] = hp[(size_t)r * TT + n];
        vv[n] = v_w[n];
    }
    __syncthreads();
    float s = v_b[0];
    const float* sxp = sx + (size_t)b * TT * NF + n;
    for (int u = 0; u < TT; u++) {
        float e = tanh_fast(sxp[(size_t)u * NF] + hv[u]);
        s += vv[u] * e;
    }
    float m = s;
#pragma unroll
    for (int off = 32; off >= 1; off >>= 1) m = fmaxf(m, __shfl_xor(m, off));
    int lane = n & 63, wid = n >> 6;
    if (lane == 0) red[wid] = m;
    __syncthreads();
    float bm = fmaxf(fmaxf(red[0], red[1]), fmaxf(red[2], red[3]));
    float p = __expf(s - bm);
    float ps = p;
#pragma unroll
    for (int off = 32; off >= 1; off >>= 1) ps += __shfl_xor(ps, off);
    if (lane == 0) red[4 + wid] = ps;
    __syncthreads();
    float denom = red[4] + red[5] + red[6] + red[7];
    float alpha = p / denom;
    size_t idx = (size_t)r * NF + n;
    out[idx] = data[idx] * alpha;
}

extern "C" void kernel_launch(void* const* d_in, const int* in_sizes, int n_in,
                              void* d_out, int out_size, void* d_ws, size_t ws_size,
                              hipStream_t stream) {
    const float* data = (const float*)d_in[0];
    const float* h0   = (const float*)d_in[1];
    const float* gk   = (const float*)d_in[2];
    const float* rk   = (const float*)d_in[3];
    const float* gb   = (const float*)d_in[4];
    const float* w1   = (const float*)d_in[5];
    const float* w1b  = (const float*)d_in[6];
    const float* w2   = (const float*)d_in[7];
    const float* w2b  = (const float*)d_in[8];
    const float* vw   = (const float*)d_in[9];
    const float* vb   = (const float*)d_in[10];
    float* out = (float*)d_out;

    float* ws  = (float*)d_ws;
    float* mxT = ws;                    // 128*1536*32 = 6291456  ([t][j][b])
    float* hs  = mxT + 6291456;         // 128*32*512  = 2097152
    float* sxb = hs + 2097152;          // 32*128*256  = 1048576
    float* hpb = sxb + 1048576;         // 128*32*128  = 524288
    float* hg2 = hpb + 524288;          // 2*512*32    = 32768
    float4* rk4 = (float4*)(hg2 + 32768);   // 262144 float4 = 4 MB

    k_hinit<<<64, 256, 0, stream>>>(h0, hg2);
    k_pack<<<1024, 256, 0, stream>>>(rk, rk4);
    k_mx<<<512, 256, 0, stream>>>(data, gk, gb, mxT);

    for (int t = 0; t < TT; t++)
        k_gstep<<<NWG, 256, 65536, stream>>>(rk4, gb, mxT, hg2, hs, t);

    k_sx<<<512, 256, 0, stream>>>(data, w1, w1b, sxb);
    k_hp<<<512, 256, 0, stream>>>(hs, w2, w2b, hpb);
    k_attn<<<4096, 256, 0, stream>>>(data, sxb, hpb, vw, vb, out);
}

// Round 14
// 1201.747 us; speedup vs baseline: 3.3729x; 1.0631x over previous
//
#include <hip/hip_runtime.h>
#include <math.h>

#define BB 32     // batch
#define TT 128    // time steps
#define NF 256    // input features
#define HH 512    // hidden
#define G3 1536   // 3*H
#define NWG 64    // GRU workgroups (column partition)

__device__ __forceinline__ float sigmoidf_(float x) { return 1.f / (1.f + __expf(-x)); }
__device__ __forceinline__ float tanh_fast(float x) {
    // 1 - 2*rcp(e^{2x}+1): rcp ~1ulp; saturates correctly (x>>0 -> 1, x<<0 -> -1)
    float e = __expf(2.f * x);
    return 1.f - 2.f * __builtin_amdgcn_rcpf(e + 1.f);
}
__device__ __forceinline__ float sel4_(float a0, float a1, float a2, float a3, int s) {
    float s01 = (s & 1) ? a1 : a0;
    float s23 = (s & 1) ? a3 : a2;
    return (s & 2) ? s23 : s01;
}

// ---------------- K0a: init h double buffer (transpose h0 -> [i][b]) ----------------
__global__ __launch_bounds__(256) void k_hinit(const float* __restrict__ h0,
                                               float* __restrict__ hg2) {
    int idx = blockIdx.x * 256 + threadIdx.x;   // 64 blocks -> 16384
    int i = idx & 511, b = idx >> 9;
    hg2[i * BB + b] = h0[b * HH + i];
}

// ---------------- K0b: pack rk into per-WG swizzled float4 blocks (r10 verbatim) ----------------
__global__ __launch_bounds__(256) void k_pack(const float* __restrict__ rk,
                                              float4* __restrict__ rk4) {
    int gidx = blockIdx.x * 256 + threadIdx.x;   // 1024 blocks -> 262144
    int wg = gidx >> 12;
    int idx = gidx & 4095;
    int k = idx >> 3, s = idx & 7;
    int jjL = s ^ (((k >> 7) & 3) << 1);
    const float* r = rk + (size_t)k * G3 + wg * 8 + jjL;
    rk4[gidx] = make_float4(r[0], r[512], r[1024], 0.f);
}

// ---------------- K1: mxT[t][j][b] — 16 batches/block (halved gk traffic) ----------------
// 256 blocks = 128 t * 2 bgroups(16 b); thread handles 6 j * 16 b.
__global__ __launch_bounds__(256) void k_mx(const float* __restrict__ data,
                                            const float* __restrict__ gk,
                                            const float* __restrict__ bias_in,
                                            float* __restrict__ mxT) {
    __shared__ __align__(16) float xs[NF * 16];   // 16 KB, [k][bb]
    int bx = blockIdx.x;
    int t = bx >> 1, b0 = (bx & 1) * 16;
    int tid = threadIdx.x;
    for (int idx = tid; idx < 16 * NF; idx += 256) {
        int bb = idx >> 8, k = idx & 255;
        xs[k * 16 + bb] = data[((size_t)(b0 + bb) * TT + t) * NF + k];
    }
    __syncthreads();
    float acc[6][16];
#pragma unroll
    for (int jj = 0; jj < 6; jj++)
#pragma unroll
        for (int bb = 0; bb < 16; bb++) acc[jj][bb] = 0.f;

#pragma unroll 2
    for (int k = 0; k < NF; k++) {
        float4 xv4[4];
#pragma unroll
        for (int q = 0; q < 4; q++) xv4[q] = *(const float4*)&xs[k * 16 + q * 4];
        const float* xv = (const float*)xv4;
#pragma unroll
        for (int jj = 0; jj < 6; jj++) {
            float g = gk[(size_t)k * G3 + jj * 256 + tid];
#pragma unroll
            for (int bb = 0; bb < 16; bb++) acc[jj][bb] += g * xv[bb];
        }
    }
#pragma unroll
    for (int jj = 0; jj < 6; jj++) {
        int j = jj * 256 + tid;
        float bi = bias_in[j];
#pragma unroll
        for (int bb = 0; bb < 16; bb++)
            mxT[((size_t)t * G3 + j) * BB + b0 + bb] = acc[jj][bb] + bi;   // [t][j][b]
    }
}

// ---------------- K2: ONE GRU STEP per launch — r10 math verbatim; global_load_lds staging ----------------
extern __shared__ float4 wl4_dyn[];   // 4096 float4 = 64 KB, r10 swizzled weight layout

__global__ __launch_bounds__(256, 1) void k_gstep(const float4* __restrict__ rk4,
                                                  const float* __restrict__ gbias,
                                                  const float* __restrict__ mxT,
                                                  float* __restrict__ hg2,
                                                  float* __restrict__ hs,
                                                  int t) {
    __shared__ __align__(16) float4 h4[HH * 8];   // 64 KB: h[k][batch-quad], swizzled
    const int tid = threadIdx.x;
    const int wg  = blockIdx.x;
    const int jj  = tid >> 5;          // 0..7 column within slice
    const int bq  = (tid >> 2) & 7;    // 0..7 batch quad
    const int ks  = tid & 3;           // 0..3 k-split (128 k each)
    const int i0  = wg * 8;
    const int i   = i0 + jj;
    const int batch = bq * 4 + ks;
    const int jjs = jj ^ (ks << 1);    // swizzled weight slot for this thread's k-range
    const int bqs = bq ^ (ks << 1);    // swizzled h slot for this thread's k-range

    // ---- stage weights: async global->LDS (proven r11/r12 path), linear dest ----
    {
        const float4* src = rk4 + (size_t)wg * 4096;
#pragma unroll
        for (int it = 0; it < 16; it++) {
            int idx = it * 256 + tid;
            __builtin_amdgcn_global_load_lds(
                (const __attribute__((address_space(1))) void*)(src + idx),
                (__attribute__((address_space(3))) void*)&wl4_dyn[idx], 16, 0, 0);
        }
    }
    // ---- stage h: linear LDS dest, PRE-SWIZZLED global source (m173 pattern) ----
    {
        const float4* hgr = (const float4*)(hg2 + (t & 1) * (HH * BB));
#pragma unroll
        for (int it = 0; it < 16; it++) {
            int idx = it * 256 + tid;
            int sidx = idx ^ ((((idx >> 10) & 3)) << 1);
            __builtin_amdgcn_global_load_lds(
                (const __attribute__((address_space(1))) void*)(hgr + sidx),
                (__attribute__((address_space(3))) void*)&h4[idx], 16, 0, 0);
        }
    }
    const float* brec = gbias + G3;
    const float bz = brec[i], br_ = brec[512 + i], bh = brec[1024 + i];
    __syncthreads();   // drains vmcnt for global_load_lds

    // mx loads — coalesced from mxT[t][j][b]
    const float* mxc = mxT + (size_t)t * G3 * BB;
    float mz = mxc[(size_t)i * BB + batch];
    float mr = mxc[(size_t)(512 + i) * BB + batch];
    float mh = mxc[(size_t)(1024 + i) * BB + batch];

    // ---- inner: 128 k per thread, 2 b128 reads + 12 FMA per k (r10 verbatim) ----
    float az0 = 0.f, az1 = 0.f, az2 = 0.f, az3 = 0.f;
    float ar0 = 0.f, ar1 = 0.f, ar2 = 0.f, ar3 = 0.f;
    float ah0 = 0.f, ah1 = 0.f, ah2 = 0.f, ah3 = 0.f;
    const float4* wp  = wl4_dyn + ks * 1024 + jjs;
    const float4* hp2 = &h4[ks * 1024 + bqs];
#pragma unroll 4
    for (int kk = 0; kk < 128; kk++) {
        float4 w = wp[kk * 8];     // {wz,wr,wc,_} col jj, k=ks*128+kk (8-way broadcast)
        float4 h = hp2[kk * 8];    // h[k][bq*4 .. bq*4+3]
        az0 += w.x * h.x; az1 += w.x * h.y; az2 += w.x * h.z; az3 += w.x * h.w;
        ar0 += w.y * h.x; ar1 += w.y * h.y; ar2 += w.y * h.z; ar3 += w.y * h.w;
        ah0 += w.z * h.x; ah1 += w.z * h.y; ah2 += w.z * h.z; ah3 += w.z * h.w;
    }

    // ---- in-wave butterfly over ks lanes (r10 verbatim) ----
    az0 += __shfl_xor(az0, 1); az1 += __shfl_xor(az1, 1);
    az2 += __shfl_xor(az2, 1); az3 += __shfl_xor(az3, 1);
    ar0 += __shfl_xor(ar0, 1); ar1 += __shfl_xor(ar1, 1);
    ar2 += __shfl_xor(ar2, 1); ar3 += __shfl_xor(ar3, 1);
    ah0 += __shfl_xor(ah0, 1); ah1 += __shfl_xor(ah1, 1);
    ah2 += __shfl_xor(ah2, 1); ah3 += __shfl_xor(ah3, 1);
    az0 += __shfl_xor(az0, 2); az1 += __shfl_xor(az1, 2);
    az2 += __shfl_xor(az2, 2); az3 += __shfl_xor(az3, 2);
    ar0 += __shfl_xor(ar0, 2); ar1 += __shfl_xor(ar1, 2);
    ar2 += __shfl_xor(ar2, 2); ar3 += __shfl_xor(ar3, 2);
    ah0 += __shfl_xor(ah0, 2); ah1 += __shfl_xor(ah1, 2);
    ah2 += __shfl_xor(ah2, 2); ah3 += __shfl_xor(ah3, 2);

    float azt = sel4_(az0, az1, az2, az3, ks);
    float art = sel4_(ar0, ar1, ar2, ar3, ks);
    float aht = sel4_(ah0, ah1, ah2, ah3, ks);

    float z = sigmoidf_(mz + azt + bz);
    float r = sigmoidf_(mr + art + br_);
    float c = tanhf(mh + r * (aht + bh));
    float hold = ((const float*)&h4[i * 8 + (bq ^ ((((i >> 7) & 3)) << 1))])[ks];
    float hn = z * hold + (1.f - z) * c;

    hg2[((t + 1) & 1) * (HH * BB) + i * BB + batch] = hn;   // coalesced across ks,bq

    // ---- hs store via LDS transpose (weights consumed -> reuse wl4_dyn region) ----
    __syncthreads();
    float* hstage = (float*)wl4_dyn;
    hstage[jj * 36 + batch] = hn;           // conflict-free (pad 36)
    __syncthreads();
    {
        int b2 = tid >> 3, ii = tid & 7;    // 32B-segment stores
        hs[((size_t)t * BB + b2) * HH + i0 + ii] = hstage[ii * 36 + b2];
    }
}

// ---------------- K3: sx[b][u][n] (upfront, r10 verbatim) ----------------
__global__ __launch_bounds__(256) void k_sx(const float* __restrict__ data,
                                            const float* __restrict__ w1,
                                            const float* __restrict__ w1b,
                                            float* __restrict__ sx) {
    int bx = blockIdx.x;
    int b = bx >> 4, ug = bx & 15;
    int n = threadIdx.x;
    float acc[8] = {0, 0, 0, 0, 0, 0, 0, 0};
    const float* dp = data + (size_t)b * TT * NF + n;
    for (int t = 0; t < TT; t++) {
        float x = dp[(size_t)t * NF];
#pragma unroll
        for (int uu = 0; uu < 8; uu++) acc[uu] += x * w1[t * TT + ug * 8 + uu];
    }
#pragma unroll
    for (int uu = 0; uu < 8; uu++) {
        int u = ug * 8 + uu;
        sx[((size_t)b * TT + u) * NF + n] = acc[uu] + w1b[u];
    }
}

// ---------------- K4: hp[r][u] = hs[r][:] @ w2 + w2b  (r10 verbatim) ----------------
__global__ __launch_bounds__(256) void k_hp(const float* __restrict__ hs,
                                            const float* __restrict__ w2,
                                            const float* __restrict__ w2b,
                                            float* __restrict__ hp) {
    __shared__ float hsl[8 * HH];   // 16KB
    int r0 = blockIdx.x * 8;
    int tid = threadIdx.x;
    for (int idx = tid; idx < 8 * HH; idx += 256)
        hsl[idx] = hs[(size_t)r0 * HH + idx];
    __syncthreads();
    int u = tid & 127, rh = tid >> 7;
    float acc[4] = {0, 0, 0, 0};
    for (int k = 0; k < HH; k++) {
        float w = w2[k * TT + u];
#pragma unroll
        for (int rr = 0; rr < 4; rr++) acc[rr] += hsl[(rh * 4 + rr) * HH + k] * w;
    }
    float wb = w2b[u];
#pragma unroll
    for (int rr = 0; rr < 4; rr++)
        hp[(size_t)(r0 + rh * 4 + rr) * TT + u] = acc[rr] + wb;
}

// ---------------- K5: fused score + softmax + output (rcp tanh + unroll) ----------------
__global__ __launch_bounds__(256) void k_attn(const float* __restrict__ data,
                                              const float* __restrict__ sx,
                                              const float* __restrict__ hp,
                                              const float* __restrict__ v_w,
                                              const float* __restrict__ v_b,
                                              float* __restrict__ out) {
    __shared__ float hv[TT];
    __shared__ float vv[TT];
    __shared__ float red[8];
    int r = blockIdx.x;
    int b = r & 31;
    int n = threadIdx.x;
    if (n < TT) {
        hv[n] = hp[(size_t)r * TT + n];
        vv[n] = v_w[n];
    }
    __syncthreads();
    float s = v_b[0];
    const float* sxp = sx + (size_t)b * TT * NF + n;
#pragma unroll 4
    for (int u = 0; u < TT; u++) {
        float e = tanh_fast(sxp[(size_t)u * NF] + hv[u]);
        s += vv[u] * e;
    }
    float m = s;
#pragma unroll
    for (int off = 32; off >= 1; off >>= 1) m = fmaxf(m, __shfl_xor(m, off));
    int lane = n & 63, wid = n >> 6;
    if (lane == 0) red[wid] = m;
    __syncthreads();
    float bm = fmaxf(fmaxf(red[0], red[1]), fmaxf(red[2], red[3]));
    float p = __expf(s - bm);
    float ps = p;
#pragma unroll
    for (int off = 32; off >= 1; off >>= 1) ps += __shfl_xor(ps, off);
    if (lane == 0) red[4 + wid] = ps;
    __syncthreads();
    float denom = red[4] + red[5] + red[6] + red[7];
    float alpha = p / denom;
    size_t idx = (size_t)r * NF + n;
    out[idx] = data[idx] * alpha;
}

extern "C" void kernel_launch(void* const* d_in, const int* in_sizes, int n_in,
                              void* d_out, int out_size, void* d_ws, size_t ws_size,
                              hipStream_t stream) {
    const float* data = (const float*)d_in[0];
    const float* h0   = (const float*)d_in[1];
    const float* gk   = (const float*)d_in[2];
    const float* rk   = (const float*)d_in[3];
    const float* gb   = (const float*)d_in[4];
    const float* w1   = (const float*)d_in[5];
    const float* w1b  = (const float*)d_in[6];
    const float* w2   = (const float*)d_in[7];
    const float* w2b  = (const float*)d_in[8];
    const float* vw   = (const float*)d_in[9];
    const float* vb   = (const float*)d_in[10];
    float* out = (float*)d_out;

    float* ws  = (float*)d_ws;
    float* mxT = ws;                    // 128*1536*32 = 6291456  ([t][j][b])
    float* hs  = mxT + 6291456;         // 128*32*512  = 2097152
    float* sxb = hs + 2097152;          // 32*128*256  = 1048576
    float* hpb = sxb + 1048576;         // 128*32*128  = 524288
    float* hg2 = hpb + 524288;          // 2*512*32    = 32768
    float4* rk4 = (float4*)(hg2 + 32768);   // 262144 float4 = 4 MB

    k_hinit<<<64, 256, 0, stream>>>(h0, hg2);
    k_pack<<<1024, 256, 0, stream>>>(rk, rk4);
    k_mx<<<256, 256, 0, stream>>>(data, gk, gb, mxT);

    for (int t = 0; t < TT; t++)
        k_gstep<<<NWG, 256, 65536, stream>>>(rk4, gb, mxT, hg2, hs, t);

    k_sx<<<512, 256, 0, stream>>>(data, w1, w1b, sxb);
    k_hp<<<512, 256, 0, stream>>>(hs, w2, w2b, hpb);
    k_attn<<<4096, 256, 0, stream>>>(data, sxb, hpb, vw, vb, out);
}